// Round 12
// baseline (292.425 us; speedup 1.0000x reference)
//
#include <hip/hip_runtime.h>
#include <math.h>

#define MTOT 9216
#define A_ 36
#define D0_ 64
#define EDGE_ 32
#define RBF_ 16
#define KNN 24
#define QIN_ 67    // D0 + KC
#define EPS_ 1e-5f

// ---- prep: state passthrough copy + pact build + xyz passthrough (fused) ----
__global__ void k_prep(const int* __restrict__ seq, const float* __restrict__ xyz,
                       const int* __restrict__ aamask,
                       const float4* __restrict__ state4, float4* __restrict__ out_state4,
                       float4* __restrict__ pact, float* __restrict__ out_xyz,
                       int* __restrict__ cnt) {
    int t = blockIdx.x * blockDim.x + threadIdx.x;
    if (t < MTOT * D0_ / 4) out_state4[t] = state4[t];
    if (t < MTOT) {
        int r = t / A_;
        int a = t - r * A_;
        int mk = (aamask[seq[r] * A_ + a] != 0);
        float x0 = xyz[t * 3 + 0], x1 = xyz[t * 3 + 1], x2 = xyz[t * 3 + 2];
        out_xyz[t * 3 + 0] = x0;
        out_xyz[t * 3 + 1] = x1;
        out_xyz[t * 3 + 2] = x2;
        if (mk) {
            int p = atomicAdd(cnt, 1);   // compiler wave-aggregates
            pact[p] = make_float4(x0, x1, x2, __int_as_float(t));
        }
    }
}

// ------- exact top-24, wave-per-atom, ballot histogram (R7 version, 84µs) ------
// NOTE: do NOT stagger the scan — lockstep same-address reads across waves are
// the L2-broadcast fast path here (R9 stagger regressed 84->~145µs).
#define CAPN 256
#define WPB 8
#define UNR 4

__global__ __launch_bounds__(512) void k_nbr(const float4* __restrict__ pact,
                                             const int* __restrict__ cnt,
                                             int* __restrict__ idx) {
    __shared__ uint2 s_cand[WPB][CAPN];   // per-wave slice, 16 KB total

    const int nact = *cnt;
    const int lane = threadIdx.x & 63;
    const int wv = threadIdx.x >> 6;
    const int slot = blockIdx.x * WPB + wv;
    if (slot >= nact) return;            // wave-uniform exit; no block barriers

    const float4 pq = pact[slot];
    const int ia = __float_as_int(pq.w);
    const unsigned long long lmask = (1ULL << lane) - 1ULL;

    unsigned cum[16];
    #pragma unroll
    for (int b = 0; b < 16; ++b) cum[b] = 0u;

    for (int base = 0; base < nact; base += 64 * UNR) {
        float4 p[UNR];
        #pragma unroll
        for (int u = 0; u < UNR; ++u) p[u] = pact[base + u * 64 + lane];  // padded: OOB-safe
        unsigned bt[UNR];
        #pragma unroll
        for (int u = 0; u < UNR; ++u) {
            int c = base + u * 64 + lane;
            int j = __float_as_int(p[u].w);
            float dx = p[u].x - pq.x, dy = p[u].y - pq.y, dz = p[u].z - pq.z;
            float d2 = dx * dx + dy * dy + dz * dz;
            bt[u] = (c < nact && j != ia) ? __float_as_uint(d2) : 0xFFFFFFFFu;
        }
        #pragma unroll
        for (int b = 0; b < 16; ++b) {
            const unsigned L = (unsigned)(242 + 2 * b) << 22;   // == bin <= 2b+1
            unsigned s = 0;
            #pragma unroll
            for (int u = 0; u < UNR; ++u)
                s += (unsigned)__popcll(__ballot(bt[u] < L));
            cum[b] += s;
        }
    }

    int bsel = 15;
    #pragma unroll
    for (int b = 15; b >= 0; --b) if (cum[b] >= KNN) bsel = b;
    const unsigned limit = (unsigned)(242 + 2 * bsel) << 22;

    int nsel = 0;
    for (int base = 0; base < nact; base += 64 * UNR) {
        float4 p[UNR];
        #pragma unroll
        for (int u = 0; u < UNR; ++u) p[u] = pact[base + u * 64 + lane];
        #pragma unroll
        for (int u = 0; u < UNR; ++u) {
            int c = base + u * 64 + lane;
            int j = __float_as_int(p[u].w);
            float dx = p[u].x - pq.x, dy = p[u].y - pq.y, dz = p[u].z - pq.z;
            float d2 = dx * dx + dy * dy + dz * dz;
            unsigned bits = (c < nact && j != ia) ? __float_as_uint(d2) : 0xFFFFFFFFu;
            bool sel = bits < limit;
            unsigned long long m = __ballot(sel);
            int pos = nsel + (int)__popcll(m & lmask);
            if (sel && pos < CAPN) s_cand[wv][pos] = make_uint2(bits, (unsigned)j);
            nsel += (int)__popcll(m);
        }
    }
    __builtin_amdgcn_wave_barrier();

    int n = min(nsel, CAPN);
    for (int c = lane; c < n; c += 64) {
        uint2 my = s_cand[wv][c];
        int rank = 0;
        for (int c2 = 0; c2 < n; ++c2) {
            uint2 o = s_cand[wv][c2];
            rank += (o.x < my.x) || (o.x == my.x && o.y < my.y);
        }
        if (rank < KNN) idx[ia * KNN + rank] = (int)my.y;
    }
}

// ------- persistent per-CU attention: weights staged in LDS once per block ----
// 256 blocks (1/CU) x 4 waves; each wave grid-strides over atoms. Weight reads
// come from LDS (the L2 weight-stream latency was the R10 bound); only Wself
// stays global (phase-rotated). Body data flow is wave-local -> wave_barrier.
#define OW_Q   0        // Wq   67*64 = 4288
#define OW_K   4288     // Wk   99*64 = 6336
#define OW_V0  10624    // Wv0  99*64 = 6336
#define OW_V1  16960    // Wv1  99*16 = 1584
#define OW_E   18544    // We   21*32 = 672
#define OW_BE  19216    // be   32
#define OW_B0  19248    // b0   64
#define OW_O0  19312    // Wo0  64*64 = 4096
#define NW_TOT 23408    // dwords = 93.6 KB

__global__ __launch_bounds__(256, 1) void k_attn(
    const float* __restrict__ xyz, const int* __restrict__ seq,
    const int* __restrict__ num_bonds, const float* __restrict__ state,
    const float* __restrict__ grads,
    const float* __restrict__ We, const float* __restrict__ be,
    const float* __restrict__ Wq, const float* __restrict__ Wk,
    const float* __restrict__ Wv0, const float* __restrict__ Wv1,
    const float* __restrict__ Wo0, const float* __restrict__ Wself,
    const float* __restrict__ b0,
    const float4* __restrict__ pact, const int* __restrict__ cnt,
    const int* __restrict__ idxbuf,
    float* __restrict__ out_xyz, float* __restrict__ out_state) {

    __shared__ float s_w[NW_TOT];             // 93.6 KB staged weights
    __shared__ float sh_kin[4][KNN][100];
    __shared__ float sh_qwk[4][4][100];       // qW -> wkin overlay
    __shared__ float sh_rbfv1[4][KNN * 16];   // rbf -> v1 overlay
    __shared__ float sh_lc[4][96];            // logits -> coef overlay
    __shared__ float sh_qo[4][64];            // q -> o0 overlay
    __shared__ float sh_dir[4][KNN][4];
    __shared__ float sh_l1j[4][KNN][3][3];
    __shared__ float sh_qin[4][68];
    __shared__ float sh_attn[4][4][KNN];
    __shared__ int   sh_j[4][KNN];
    __shared__ int   sh_ok[4][KNN];
    __shared__ int   sh_bc[4][KNN];
    __shared__ float sh_xi[4][4];

    const int nact = *cnt;
    const int tid = threadIdx.x;

    // ---- stage all weights into LDS (once per block) ----
    #define STG(off, src, n4) \
        for (int u = tid; u < (n4); u += 256) ((float4*)&s_w[off])[u] = ((const float4*)(src))[u];
    STG(OW_Q,  Wq,  1072)
    STG(OW_K,  Wk,  1584)
    STG(OW_V0, Wv0, 1584)
    STG(OW_V1, Wv1, 396)
    STG(OW_E,  We,  168)
    STG(OW_BE, be,  8)
    STG(OW_B0, b0,  16)
    STG(OW_O0, Wo0, 1024)
    #undef STG
    __syncthreads();

    const int w = tid >> 6;
    const int lane = tid & 63;
    const int l15 = lane & 15;
    const int h = lane >> 4;
    const int wgid = blockIdx.x * 4 + w;
    const int iters = (nact + 1023) >> 10;

    float (*s_kin)[100] = sh_kin[w];
    float (*s_qwk)[100] = sh_qwk[w];
    float* s_rbfv1      = sh_rbfv1[w];
    float* s_lc         = sh_lc[w];
    float* s_qo         = sh_qo[w];
    float (*s_dir)[4]   = sh_dir[w];
    float (*s_l1j)[3][3]= sh_l1j[w];
    float* s_qin        = sh_qin[w];
    float (*s_attn)[KNN]= sh_attn[w];
    int* s_j            = sh_j[w];
    int* s_ok           = sh_ok[w];
    int* s_bc           = sh_bc[w];
    float* s_xi         = sh_xi[w];

    for (int it = 0; it < iters; ++it) {
        int slot = wgid + (it << 10);
        slot = min(slot, nact - 1);           // tail dupes write identical values
        const int i = __float_as_int(pact[slot].w);
        const int ph64 = (int)(((unsigned)slot * 7u) & 63u);   // Wself stream phase

        // ---- stage per-atom inputs ----
        s_qin[lane] = state[i * D0_ + lane];
        if (lane < 3) {
            float g0 = grads[(lane * MTOT + i) * 3 + 0];
            float g1 = grads[(lane * MTOT + i) * 3 + 1];
            float g2 = grads[(lane * MTOT + i) * 3 + 2];
            s_qin[D0_ + lane] = sqrtf(g0 * g0 + g1 * g1 + g2 * g2 + EPS_);
            s_xi[lane] = xyz[i * 3 + lane];
        }
        if (lane < KNN) {
            int j = idxbuf[i * KNN + lane];
            int ok = (j >= 0 && j < MTOT);
            int jj = ok ? j : 0;
            s_j[lane] = jj;
            s_ok[lane] = ok;
            float dx = xyz[jj * 3 + 0] - xyz[i * 3 + 0];
            float dy = xyz[jj * 3 + 1] - xyz[i * 3 + 1];
            float dz = xyz[jj * 3 + 2] - xyz[i * 3 + 2];
            float dist = sqrtf(dx * dx + dy * dy + dz * dz + EPS_);
            s_dir[lane][0] = dx / dist;
            s_dir[lane][1] = dy / dist;
            s_dir[lane][2] = dz / dist;
            s_dir[lane][3] = dist;
            int ri = i / A_, ai = i - ri * A_;
            int rj = jj / A_, aj = jj - rj * A_;
            int b = 0;
            if (rj == ri) b = num_bonds[(seq[ri] * A_ + ai) * A_ + aj];
            s_bc[lane] = min(max(b, 0), 4);
        }
        __builtin_amdgcn_wave_barrier();

        // ---- q projection (LDS weights) -> s_qo ----
        {
            float q = 0.0f;
            for (int c = 0; c < QIN_; ++c) q += s_qin[c] * s_w[OW_Q + c * 64 + lane];
            s_qo[lane] = q;
        }
        // ---- rbf -> s_rbfv1 ----
        for (int f = lane; f < KNN * RBF_; f += 64) {
            int k = f >> 4, r = f & 15;
            float mu = (6.0f / 15.0f) * (float)r;
            float d = s_dir[k][3] - mu;
            s_rbfv1[k * 16 + r] = expf(-d * d * 2.0f);
        }
        // ---- neighbor node0 gather ----
        for (int k = 0; k < KNN; ++k) s_kin[k][lane] = state[s_j[k] * D0_ + lane];
        // ---- l1 invariants + stash l1j ----
        for (int f = lane; f < KNN * 3; f += 64) {
            int k = f / 3, c = f - 3 * k;
            int jj = s_j[k];
            float g0 = grads[(c * MTOT + jj) * 3 + 0];
            float g1 = grads[(c * MTOT + jj) * 3 + 1];
            float g2 = grads[(c * MTOT + jj) * 3 + 2];
            s_l1j[k][c][0] = g0; s_l1j[k][c][1] = g1; s_l1j[k][c][2] = g2;
            s_kin[k][96 + c] = g0 * s_dir[k][0] + g1 * s_dir[k][1] + g2 * s_dir[k][2];
        }
        if (lane < KNN) s_kin[lane][99] = 0.0f;
        __builtin_amdgcn_wave_barrier();

        // ---- edge embedding -> kin[:, 64:96] (LDS We) ----
        for (int f = lane; f < KNN * EDGE_; f += 64) {
            int k = f >> 5, d = f & 31;
            float acc = s_w[OW_BE + d] + s_w[OW_E + (RBF_ + s_bc[k]) * EDGE_ + d];
            #pragma unroll
            for (int r = 0; r < RBF_; ++r)
                acc += s_rbfv1[k * 16 + r] * s_w[OW_E + r * EDGE_ + d];
            s_kin[k][64 + d] = acc;
        }
        // ---- fold q into Wk -> s_qwk (LDS Wk) ----
        for (int t = 0; t < 7; ++t) {
            int c = t * 16 + l15;
            if (c < 99) {
                const float* wk = &s_w[OW_K + c * 64 + h * 16];
                float acc = 0.0f;
                #pragma unroll
                for (int d = 0; d < 16; ++d) acc += s_qo[h * 16 + d] * wk[d];
                s_qwk[h][c] = acc;
            }
        }
        __builtin_amdgcn_wave_barrier();

        // ---- logits[h][k] = kin[k] . qW[h] -> s_lc ----
        for (int f = lane; f < 96; f += 64) {
            int k = f >> 2, hh = f & 3;
            const float4* k4 = (const float4*)s_kin[k];
            const float4* q4 = (const float4*)s_qwk[hh];
            float acc = 0.0f;
            #pragma unroll
            for (int c4 = 0; c4 < 24; ++c4) {
                float4 a = k4[c4], b = q4[c4];
                acc += a.x * b.x + a.y * b.y + a.z * b.z + a.w * b.w;
            }
            acc += s_kin[k][96] * s_qwk[hh][96] + s_kin[k][97] * s_qwk[hh][97]
                 + s_kin[k][98] * s_qwk[hh][98];
            s_lc[hh * 24 + k] = s_ok[k] ? acc * 0.25f : -1e9f;
        }
        __builtin_amdgcn_wave_barrier();

        // ---- softmax ----
        float attn[KNN];
        {
            float mx = -1e30f;
            #pragma unroll
            for (int k = 0; k < KNN; ++k) { attn[k] = s_lc[h * 24 + k]; mx = fmaxf(mx, attn[k]); }
            float ss = 0.0f;
            #pragma unroll
            for (int k = 0; k < KNN; ++k) { attn[k] = expf(attn[k] - mx); ss += attn[k]; }
            float rs = 1.0f / ss;
            #pragma unroll
            for (int k = 0; k < KNN; ++k) attn[k] *= rs;
        }
        __builtin_amdgcn_wave_barrier();
        s_attn[h][l15] = attn[l15];
        if (l15 < 8) s_attn[h][16 + l15] = attn[16 + l15];

        // ---- wkin[h][c] = sum_k attn[k]*kin[k][c] -> s_qwk overlay ----
        for (int t = 0; t < 7; ++t) {
            int c = t * 16 + l15;
            if (c < 99) {
                float acc = 0.0f;
                #pragma unroll
                for (int k = 0; k < KNN; ++k) acc += attn[k] * s_kin[k][c];
                s_qwk[h][c] = acc;
            }
        }
        // ---- v1[k][u] = kin[k] . Wv1[:,u] -> s_rbfv1 overlay (LDS Wv1) ----
        for (int t = 0; t < 6; ++t) {
            int k = (t * 64 + lane) >> 4;
            const float4* k4 = (const float4*)s_kin[k];
            const float* wv = &s_w[OW_V1 + l15];
            float acc = 0.0f;
            #pragma unroll
            for (int c4 = 0; c4 < 24; ++c4) {
                float4 a = k4[c4];
                acc += a.x * wv[(c4 * 4 + 0) * 16] + a.y * wv[(c4 * 4 + 1) * 16]
                     + a.z * wv[(c4 * 4 + 2) * 16] + a.w * wv[(c4 * 4 + 3) * 16];
            }
            acc += s_kin[k][96] * wv[96 * 16] + s_kin[k][97] * wv[97 * 16]
                 + s_kin[k][98] * wv[98 * 16];
            s_rbfv1[k * 16 + l15] = acc;
        }
        __builtin_amdgcn_wave_barrier();

        // ---- o0[lane] = wkin[h] . Wv0[:, lane] (LDS Wv0) -> s_qo overlay ----
        {
            float o0 = 0.0f;
            for (int c = 0; c < 99; ++c) o0 += s_qwk[h][c] * s_w[OW_V0 + c * 64 + lane];
            __builtin_amdgcn_wave_barrier();
            s_qo[lane] = o0;
        }
        __builtin_amdgcn_wave_barrier();

        // ---- out0 = o0 @ Wo0 (LDS) + node0 @ Wself (global, phased) + b0 ----
        {
            float acc = s_w[OW_B0 + lane];
            for (int t = 0; t < 64; ++t) acc += s_qo[t] * s_w[OW_O0 + t * 64 + lane];
            for (int t = 0; t < 64; ++t) {
                int t2 = (t + ph64) & 63;
                acc += s_qin[t2] * Wself[t2 * 64 + lane];
            }
            out_state[i * D0_ + lane] = acc;
        }
        // ---- coef[k][c] = sum_h attn[h][k] * v1[k][h*4+c] -> s_lc overlay ----
        for (int f = lane; f < KNN * 4; f += 64) {
            int k = f >> 2, c = f & 3;
            float a2 = 0.0f;
            #pragma unroll
            for (int hh = 0; hh < 4; ++hh) a2 += s_attn[hh][k] * s_rbfv1[k * 16 + hh * 4 + c];
            s_lc[k * 4 + c] = a2;
        }
        __builtin_amdgcn_wave_barrier();

        // ---- vector message -> xyz shift ----
        if (lane < 3) {
            float o1 = 0.0f;
            #pragma unroll
            for (int k = 0; k < KNN; ++k) {
                float t = s_lc[k * 4 + 0] * s_dir[k][lane];
                t += s_lc[k * 4 + 1] * s_l1j[k][0][lane];
                t += s_lc[k * 4 + 2] * s_l1j[k][1][lane];
                t += s_lc[k * 4 + 3] * s_l1j[k][2][lane];
                o1 += t;
            }
            out_xyz[i * 3 + lane] = s_xi[lane] + o1 / 100.0f;
        }
        __builtin_amdgcn_wave_barrier();
    }
}

extern "C" void kernel_launch(void* const* d_in, const int* in_sizes, int n_in,
                              void* d_out, int out_size, void* d_ws, size_t ws_size,
                              hipStream_t stream) {
    const int*   seq    = (const int*)d_in[0];
    const float* xyz    = (const float*)d_in[1];
    const int*   aamask = (const int*)d_in[2];
    const int*   nbonds = (const int*)d_in[3];
    const float* state  = (const float*)d_in[4];
    const float* grads  = (const float*)d_in[5];
    const float* We    = (const float*)d_in[7];
    const float* be    = (const float*)d_in[8];
    const float* Wq    = (const float*)d_in[9];
    const float* Wk    = (const float*)d_in[10];
    const float* Wv0   = (const float*)d_in[11];
    const float* Wv1   = (const float*)d_in[12];
    const float* Wo0   = (const float*)d_in[13];
    const float* Wself = (const float*)d_in[14];
    const float* b0    = (const float*)d_in[15];

    float* out_xyz   = (float*)d_out;
    float* out_state = out_xyz + MTOT * 3;

    char* ws = (char*)d_ws;
    int*    cnt  = (int*)ws;                              // 16 B
    float4* pact = (float4*)(ws + 16);                    // (MTOT+256)*16 = 151552 B
    int*    idx  = (int*)(ws + 16 + 151552);              // 884736 B

    hipMemsetAsync(cnt, 0, 16, stream);
    k_prep<<<(MTOT * D0_ / 4 + 255) / 256, 256, 0, stream>>>(
        seq, xyz, aamask, (const float4*)state, (float4*)out_state,
        pact, out_xyz, cnt);
    k_nbr<<<(MTOT + WPB - 1) / WPB, 512, 0, stream>>>(pact, cnt, idx);
    k_attn<<<256, 256, 0, stream>>>(xyz, seq, nbonds, state, grads, We, be, Wq, Wk,
                                    Wv0, Wv1, Wo0, Wself, b0, pact, cnt, idx,
                                    out_xyz, out_state);
}